// Round 4
// baseline (499.464 us; speedup 1.0000x reference)
//
#include <hip/hip_runtime.h>

// SparseMinCostFlow — 3-launch version.
// N=8192, E=262144, 10 iterations, dense NxN fp32 out (256 MB).
//
// Lessons so far:
//  - Harness floor ~215us of poison-fill sits inside the timed window.
//  - Graph-node launch overhead ~10us each => 11 launches wasted ~100us (r3).
//  - Round 2's in-kernel barrier disaster was the ACQUIRE polls: each
//    agent-scope acquire load emits a cache invalidate (buffer_inv), and 256
//    hot spinners invalidated all XCD L2s continuously -> 4.2 GB refetch.
//    Fix: RELAXED polls (no invalidate, coherent via L3) + s_sleep(16) +
//    a single acquire fence after the wait; no long-lived spins.
//
// Structure (3 stream ops):
//   hipMemsetAsync      : zero inflow buffers + barrier counter (320 KB)
//   fused_flow_zero     : flow team (128 blocks) runs iterations 1..9 with 8
//                         internal sleepy barriers, edge data cached in regs;
//                         zero team (1920 blocks) clears the 256 MB output.
//                         The two teams never interact.
//   scatter_final       : iter 10 -> atomicAdd into the zeroed dense output
//                         (kernel boundary = zero-done ordering, for free).

#define NN 8192
#define EE 262144
#define THREADS 256
#define FBLK 128
#define EPT 8                        // EE / (FBLK*THREADS)
#define TOTBLK 2048
#define ZBLK (TOTBLK - FBLK)
#define N4 ((long)NN * NN / 4)       // 16,777,216 float4 in output

__global__ void __launch_bounds__(THREADS) fused_flow_zero(
        const float* __restrict__ values, const float* __restrict__ dem,
        const int* __restrict__ rows, const int* __restrict__ cols,
        float* __restrict__ inflow, unsigned* __restrict__ ctr,
        float4* __restrict__ out4) {
    const int bid = blockIdx.x;
    if (bid < FBLK) {
        // ---------------- flow team: iterations 1..9 ----------------
        const int t = bid * THREADS + threadIdx.x;          // 0..32767
        int r[EPT], c[EPT];
        float v[EPT], dr[EPT];
        #pragma unroll
        for (int j = 0; j < EPT; ++j) {
            int e = t + j * (FBLK * THREADS);               // coalesced
            r[j] = rows[e]; c[j] = cols[e]; v[j] = values[e];
        }
        #pragma unroll
        for (int j = 0; j < EPT; ++j) dr[j] = dem[r[j]];

        // Iteration 1: inflow_0 == 0  =>  adj = relu(0 - d[r]).
        {
            float* next = inflow + NN;
            #pragma unroll
            for (int j = 0; j < EPT; ++j)
                atomicAdd(&next[c[j]], v[j] * fmaxf(-dr[j], 0.f));
        }

        for (int it = 2; it <= 9; ++it) {
            // --- flow-team barrier: arrive(release) + RELAXED sleepy poll ---
            __syncthreads();
            if (threadIdx.x == 0) {
                __hip_atomic_fetch_add(ctr, 1u, __ATOMIC_RELEASE,
                                       __HIP_MEMORY_SCOPE_AGENT);
                const unsigned target = (unsigned)((it - 1) * FBLK); // monotonic
                while (__hip_atomic_load(ctr, __ATOMIC_RELAXED,
                                         __HIP_MEMORY_SCOPE_AGENT) < target)
                    __builtin_amdgcn_s_sleep(16);           // ~0.4us per poll
            }
            __syncthreads();
            __threadfence();  // ONE acquire: drop stale L1/L2 before gathers

            const float* prev = inflow + (long)(it - 1) * NN;
            float*       next = inflow + (long)it * NN;
            #pragma unroll
            for (int j = 0; j < EPT; ++j) {
                float adj = fmaxf(prev[r[j]] - dr[j], 0.f);
                atomicAdd(&next[c[j]], v[j] * adj);
            }
        }
        // inflow_9 complete at kernel end; scatter kernel consumes it.
    } else {
        // ---------------- zero team: clear 256 MB output ----------------
        long i = (long)(bid - FBLK) * THREADS + threadIdx.x;
        const long stride = (long)ZBLK * THREADS;
        const float4 z = make_float4(0.f, 0.f, 0.f, 0.f);
        for (; i < N4; i += stride) out4[i] = z;
    }
}

__global__ void __launch_bounds__(THREADS) scatter_final(
        const float* __restrict__ values, const float* __restrict__ dem,
        const int* __restrict__ rows, const int* __restrict__ cols,
        const float* __restrict__ inflow_prev, float* __restrict__ out) {
    int e = blockIdx.x * THREADS + threadIdx.x;
    int r = rows[e];
    float adj = fmaxf(inflow_prev[r] - dem[r], 0.f);
    atomicAdd(&out[(long)r * NN + cols[e]], values[e] * adj);
}

extern "C" void kernel_launch(void* const* d_in, const int* in_sizes, int n_in,
                              void* d_out, int out_size, void* d_ws, size_t ws_size,
                              hipStream_t stream) {
    const float* values = (const float*)d_in[0];
    const float* dem    = (const float*)d_in[1];
    const int*   rows   = (const int*)d_in[2];
    const int*   cols   = (const int*)d_in[3];
    float* out = (float*)d_out;

    // ws: inflow_0..inflow_9 (10*NN floats; slot 0 unused) + barrier counter.
    float*    inflow = (float*)d_ws;
    unsigned* ctr    = (unsigned*)((char*)d_ws + 10L * NN * sizeof(float));

    hipMemsetAsync(d_ws, 0, 10L * NN * sizeof(float) + 64, stream);

    fused_flow_zero<<<TOTBLK, THREADS, 0, stream>>>(
        values, dem, rows, cols, inflow, ctr, (float4*)out);

    scatter_final<<<EE / THREADS, THREADS, 0, stream>>>(
        values, dem, rows, cols, inflow + 9L * NN, out);
}

// Round 5
// 407.724 us; speedup vs baseline: 1.2250x; 1.2250x over previous
//
#include <hip/hip_runtime.h>

// SparseMinCostFlow — 3-launch, FENCE-FREE cross-block protocol.
// N=8192, E=262144, 10 iterations, dense NxN fp32 out (256 MB).
//
// Lessons:
//  r2: acquire-polling barrier -> buffer_inv per poll -> 800us.
//  r4: relaxed poll but __threadfence per barrier -> 4096 agent-scope L2
//      writeback+invalidate ops -> zero team throttled to 1.2 TB/s, +75MB
//      extra L2 writebacks, 273us. Agent fences in hot kernels = L2 flush
//      storms on 8-XCD MI355X.
//  Fix: route ALL cross-block data through the coherence point so NO fence
//  is needed:
//    - inflow writes: device-scope atomicAdd (RMW at coherence point).
//    - inflow reads:  __hip_atomic_load(RELAXED, AGENT) — sc-bit load that
//      bypasses stale L1/L2, emits no cache invalidate.
//    - barrier: __syncthreads (s_waitcnt vmcnt(0) drains our atomics) then
//      relaxed fetch-add arrive + relaxed sleepy poll. Monotonic target.
//  Kernel boundary (implicit L2 writeback + invalidate) provides visibility
//  of the zero-fill and inflow_9 to the final scatter kernel.

#define NN 8192
#define EE 262144
#define THREADS 256
#define FBLK 128
#define EPT 8                        // EE / (FBLK*THREADS)
#define TOTBLK 2048                  // 8 blocks/CU * 256 CU: all co-resident
#define ZBLK (TOTBLK - FBLK)
#define N4 ((long)NN * NN / 4)       // 16,777,216 float4 in output

__global__ void __launch_bounds__(THREADS) fused_flow_zero(
        const float* __restrict__ values, const float* __restrict__ dem,
        const int* __restrict__ rows, const int* __restrict__ cols,
        float* __restrict__ inflow, unsigned* __restrict__ ctr,
        float4* __restrict__ out4) {
    const int bid = blockIdx.x;
    if (bid < FBLK) {
        // ---------------- flow team: iterations 1..9 ----------------
        const int t = bid * THREADS + threadIdx.x;          // 0..32767
        int r[EPT], c[EPT];
        float v[EPT], dr[EPT];
        #pragma unroll
        for (int j = 0; j < EPT; ++j) {
            int e = t + j * (FBLK * THREADS);               // coalesced
            r[j] = rows[e]; c[j] = cols[e]; v[j] = values[e];
        }
        #pragma unroll
        for (int j = 0; j < EPT; ++j) dr[j] = dem[r[j]];

        // Iteration 1: inflow_0 == 0  =>  adj = relu(0 - d[r]).
        {
            float* next = inflow + NN;
            #pragma unroll
            for (int j = 0; j < EPT; ++j)
                atomicAdd(&next[c[j]], v[j] * fmaxf(-dr[j], 0.f));
        }

        for (int it = 2; it <= 9; ++it) {
            // --- fence-free flow-team barrier ---
            // __syncthreads drains each wave's outstanding atomics
            // (s_waitcnt vmcnt(0)) before the leader arrives.
            __syncthreads();
            if (threadIdx.x == 0) {
                __hip_atomic_fetch_add(ctr, 1u, __ATOMIC_RELAXED,
                                       __HIP_MEMORY_SCOPE_AGENT);
                const unsigned target = (unsigned)((it - 1) * FBLK);
                while (__hip_atomic_load(ctr, __ATOMIC_RELAXED,
                                         __HIP_MEMORY_SCOPE_AGENT) < target)
                    __builtin_amdgcn_s_sleep(8);            // ~0.2us per poll
            }
            __syncthreads();
            // NO fence: gathers below bypass stale caches via sc-bit loads.

            const float* prev = inflow + (long)(it - 1) * NN;
            float*       next = inflow + (long)it * NN;
            #pragma unroll
            for (int j = 0; j < EPT; ++j) {
                float pv = __hip_atomic_load(&prev[r[j]], __ATOMIC_RELAXED,
                                             __HIP_MEMORY_SCOPE_AGENT);
                float adj = fmaxf(pv - dr[j], 0.f);
                atomicAdd(&next[c[j]], v[j] * adj);
            }
        }
        // inflow_9 complete at kernel end; visibility to the scatter kernel
        // comes from the dispatch-boundary release/acquire.
    } else {
        // ---------------- zero team: clear 256 MB output ----------------
        long i = (long)(bid - FBLK) * THREADS + threadIdx.x;
        const long stride = (long)ZBLK * THREADS;
        const float4 z = make_float4(0.f, 0.f, 0.f, 0.f);
        for (; i < N4; i += stride) out4[i] = z;
    }
}

__global__ void __launch_bounds__(THREADS) scatter_final(
        const float* __restrict__ values, const float* __restrict__ dem,
        const int* __restrict__ rows, const int* __restrict__ cols,
        const float* __restrict__ inflow_prev, float* __restrict__ out) {
    int e = blockIdx.x * THREADS + threadIdx.x;
    int r = rows[e];
    float adj = fmaxf(inflow_prev[r] - dem[r], 0.f);
    atomicAdd(&out[(long)r * NN + cols[e]], values[e] * adj);
}

extern "C" void kernel_launch(void* const* d_in, const int* in_sizes, int n_in,
                              void* d_out, int out_size, void* d_ws, size_t ws_size,
                              hipStream_t stream) {
    const float* values = (const float*)d_in[0];
    const float* dem    = (const float*)d_in[1];
    const int*   rows   = (const int*)d_in[2];
    const int*   cols   = (const int*)d_in[3];
    float* out = (float*)d_out;

    // ws: inflow_0..inflow_9 (slot 0 logically zero, unused) + barrier ctr.
    float*    inflow = (float*)d_ws;
    unsigned* ctr    = (unsigned*)((char*)d_ws + 10L * NN * sizeof(float));

    hipMemsetAsync(d_ws, 0, 10L * NN * sizeof(float) + 64, stream);

    fused_flow_zero<<<TOTBLK, THREADS, 0, stream>>>(
        values, dem, rows, cols, inflow, ctr, (float4*)out);

    scatter_final<<<EE / THREADS, THREADS, 0, stream>>>(
        values, dem, rows, cols, inflow + 9L * NN, out);
}

// Round 6
// 405.923 us; speedup vs baseline: 1.2304x; 1.0044x over previous
//
#include <hip/hip_runtime.h>

// SparseMinCostFlow — 2-launch, atomic-free inflow accumulation.
// N=8192, E=262144, 10 iterations, dense NxN fp32 out (256 MB).
//
// Key lesson (r1/r3/r5 invariant): 262k global atomicAdds onto 8192 words
// (512 cache lines) cost ~16-19us/stage regardless of sync mechanism —
// same-LINE RMWs serialize at the coherence point (~512 RMW/line).
// Fix: per-block LDS accumulation + plain coalesced partial flush + col-sliced
// reduction. ZERO global atomics in the iteration chain.
//
// Sync: per-block flag words (no RMW contention; own-word writes + one
// polling wave with s_sleep). MAGIC != 0xAA poison => no init/memset needed.
// All cross-block data moves via relaxed agent-scope atomics (sc-bypass, no
// cache-maintenance ops). __syncthreads (s_waitcnt vmcnt(0)) before each flag
// store orders data ahead of the flag.
//
// Launch 1: fused_flow_zero (512 blocks x 1024 thr, exactly 2/CU resident):
//   blocks 0..31  : flow team, stages 1..9 -> adjg[1..9]
//   blocks 32..511: zero the 256 MB output (flow chain hides under this)
// Launch 2: scatter_final: out[r*N+c] += values[e] * adjg[9][rows[e]]
//   (262k atomics to ~distinct lines => no line serialization).

#define NN 8192
#define EE 262144
#define FBLK 32
#define TOTBLK 512
#define ZBLK (TOTBLK - FBLK)
#define THREADS 1024
#define EPB (EE / FBLK)          // 8192 edges per flow block
#define EPT (EPB / THREADS)      // 8 edges per thread (contiguous)
#define SLICE (NN / FBLK)        // 256 cols per block in reduce phase
#define N4 ((long)NN * NN / 4)   // float4 count in output
#define MAGIC 0x5CA1AB1Eu        // != 0xAAAAAAAA ws poison, != 0

#define LOAD_A(p)    __hip_atomic_load((p),  __ATOMIC_RELAXED, __HIP_MEMORY_SCOPE_AGENT)
#define STORE_A(p,v) __hip_atomic_store((p), (v), __ATOMIC_RELAXED, __HIP_MEMORY_SCOPE_AGENT)

__global__ void __launch_bounds__(THREADS) fused_flow_zero(
        const float* __restrict__ values, const float* __restrict__ dem,
        const int* __restrict__ rows, const int* __restrict__ cols,
        float* __restrict__ partial,   // FBLK * NN floats
        float* __restrict__ adjg,      // 10 * NN floats (s=1..9 used)
        unsigned* __restrict__ flags,  // 20 * 64 words, per-(stage,phase) lines
        float4* __restrict__ out4) {
    __shared__ float adjLDS[NN];       // 32 KB
    __shared__ float accLDS[NN];       // 32 KB  (64 KB total -> 2 blocks/CU)
    const int bid = blockIdx.x;
    const int tid = threadIdx.x;

    if (bid < FBLK) {
        // ---------------- flow team ----------------
        const int ebase = bid * EPB + tid * EPT;        // 32B-aligned
        const int4*   r4 = (const int4*)(rows + ebase);
        const int4*   c4 = (const int4*)(cols + ebase);
        const float4* v4 = (const float4*)(values + ebase);

        for (int s = 1; s <= 9; ++s) {
            // ---- phase 1: adjLDS = adj_{s-1}, accLDS = 0 ----
            if (s == 1) {
                #pragma unroll
                for (int j = 0; j < NN / THREADS; ++j) {
                    int c = tid + j * THREADS;
                    adjLDS[c] = fmaxf(-dem[c], 0.f);    // adj0 = relu(0 - d)
                    accLDS[c] = 0.f;
                }
            } else {
                const float* src = adjg + (long)(s - 1) * NN;
                #pragma unroll
                for (int j = 0; j < NN / THREADS; ++j) {
                    int c = tid + j * THREADS;
                    adjLDS[c] = LOAD_A(&src[c]);
                    accLDS[c] = 0.f;
                }
            }
            __syncthreads();

            // ---- phase 2: accumulate partial inflow_s in LDS ----
            {
                int4 ra = r4[0], rb = r4[1];
                int4 ca = c4[0], cb = c4[1];
                float4 va = v4[0], vb = v4[1];
                atomicAdd(&accLDS[ca.x], va.x * adjLDS[ra.x]);
                atomicAdd(&accLDS[ca.y], va.y * adjLDS[ra.y]);
                atomicAdd(&accLDS[ca.z], va.z * adjLDS[ra.z]);
                atomicAdd(&accLDS[ca.w], va.w * adjLDS[ra.w]);
                atomicAdd(&accLDS[cb.x], vb.x * adjLDS[rb.x]);
                atomicAdd(&accLDS[cb.y], vb.y * adjLDS[rb.y]);
                atomicAdd(&accLDS[cb.z], vb.z * adjLDS[rb.z]);
                atomicAdd(&accLDS[cb.w], vb.w * adjLDS[rb.w]);
            }
            __syncthreads();

            // ---- flush my partial vector (plain-rate coalesced stores) ----
            {
                float* pb = partial + (long)bid * NN;
                #pragma unroll
                for (int j = 0; j < NN / THREADS; ++j) {
                    int c = tid + j * THREADS;
                    STORE_A(&pb[c], accLDS[c]);
                }
            }
            __syncthreads();   // s_waitcnt vmcnt(0): partials at coherence pt

            // ---- sync1: wait for all blocks' stage-s partials ----
            {
                unsigned* fl = flags + (2 * s) * 64;
                if (tid == 0) STORE_A(&fl[bid], MAGIC);
                asm volatile("" ::: "memory");
                if (tid < 64) {
                    for (;;) {
                        unsigned f = (tid < FBLK) ? LOAD_A(&fl[tid]) : MAGIC;
                        if (__all(f == MAGIC)) break;
                        __builtin_amdgcn_s_sleep(4);    // ~0.1 us
                    }
                }
                asm volatile("" ::: "memory");
                __syncthreads();
            }

            // ---- phase 3: reduce my 256-col slice -> adjg[s] ----
            if (tid < SLICE) {
                int c = bid * SLICE + tid;
                float ssum = 0.f;
                #pragma unroll 8
                for (int j = 0; j < FBLK; ++j)
                    ssum += LOAD_A(&partial[(long)j * NN + c]);
                STORE_A(&adjg[(long)s * NN + c], fmaxf(ssum - dem[c], 0.f));
            }
            __syncthreads();   // drain adjg stores before flagging

            // ---- sync2: adjg[s] visible (skip at s=9: dispatch boundary) ----
            if (s < 9) {
                unsigned* fl = flags + (2 * s + 1) * 64;
                if (tid == 0) STORE_A(&fl[bid], MAGIC);
                asm volatile("" ::: "memory");
                if (tid < 64) {
                    for (;;) {
                        unsigned f = (tid < FBLK) ? LOAD_A(&fl[tid]) : MAGIC;
                        if (__all(f == MAGIC)) break;
                        __builtin_amdgcn_s_sleep(4);
                    }
                }
                asm volatile("" ::: "memory");
                __syncthreads();
            }
        }
    } else {
        // ---------------- zero team: clear 256 MB output ----------------
        long i = (long)(bid - FBLK) * THREADS + tid;
        const long stride = (long)ZBLK * THREADS;
        const float4 z = make_float4(0.f, 0.f, 0.f, 0.f);
        for (; i < N4; i += stride) out4[i] = z;
    }
}

__global__ void __launch_bounds__(256) scatter_final(
        const float* __restrict__ values,
        const int* __restrict__ rows, const int* __restrict__ cols,
        const float* __restrict__ adj9, float* __restrict__ out) {
    int e = blockIdx.x * 256 + threadIdx.x;
    int r = rows[e];
    float a = adj9[r];                       // plain load: 32 KB, L1-resident
    atomicAdd(&out[(long)r * NN + cols[e]], values[e] * a);
}

extern "C" void kernel_launch(void* const* d_in, const int* in_sizes, int n_in,
                              void* d_out, int out_size, void* d_ws, size_t ws_size,
                              hipStream_t stream) {
    const float* values = (const float*)d_in[0];
    const float* dem    = (const float*)d_in[1];
    const int*   rows   = (const int*)d_in[2];
    const int*   cols   = (const int*)d_in[3];
    float* out = (float*)d_out;

    float*    partial = (float*)d_ws;                                // 1 MB
    float*    adjg    = partial + (long)FBLK * NN;                   // 320 KB
    unsigned* flags   = (unsigned*)(adjg + 10L * NN);                // 5 KB

    fused_flow_zero<<<TOTBLK, THREADS, 0, stream>>>(
        values, dem, rows, cols, partial, adjg, flags, (float4*)out);

    scatter_final<<<EE / 256, 256, 0, stream>>>(
        values, rows, cols, adjg + 9L * NN, out);
}